// Round 4
// baseline (607.275 us; speedup 1.0000x reference)
//
#include <hip/hip_runtime.h>
#include <stdint.h>

#define MROWS 8192
#define NGT   8192
#define KC    8
#define THRESH_BITS 0x40A00000u  // __float_as_uint(5.0f)

// Exact same fp32 ops/association as numpy: diff, square, left-to-right sum, IEEE sqrt.
// No FMA contraction so comparisons are bit-identical to the reference.
__device__ __forceinline__ unsigned dist_bits(float px, float py, float pz,
                                              float gx, float gy, float gz) {
#pragma clang fp contract(off)
  float dx = px - gx;
  float dy = py - gy;
  float dz = pz - gz;
  float s = (dx * dx + dy * dy) + dz * dz;
  return __float_as_uint(sqrtf(s));  // d >= 0, bits order == float order
}

__device__ __forceinline__ unsigned long long wave_min64(unsigned long long v) {
#pragma unroll
  for (int off = 32; off >= 1; off >>= 1) {
    unsigned long long o = __shfl_xor(v, off, 64);
    v = (o < v) ? o : v;
  }
  return v;
}

// ---------------- Kernel A: exact top-8 (d_bits, idx) lex-smallest per row ----------------
__global__ __launch_bounds__(256) void topk_kernel(const float* __restrict__ pred,
                                                   const float* __restrict__ gt,
                                                   uint2* __restrict__ cand) {
  __shared__ float sx[NGT], sy[NGT], sz[NGT];  // 96 KB SoA
  int tid = threadIdx.x;
  for (int j = tid; j < NGT; j += 256) {
    sx[j] = gt[j * 7 + 0];
    sy[j] = gt[j * 7 + 1];
    sz[j] = gt[j * 7 + 2];
  }
  __syncthreads();

  int lane = tid & 63;
  int wave = (blockIdx.x * 256 + tid) >> 6;
  const int nwaves = gridDim.x * 4;

  for (int row = wave; row < MROWS; row += nwaves) {
    float px = pred[row * 7 + 0];
    float py = pred[row * 7 + 1];
    float pz = pred[row * 7 + 2];

    // per-lane sorted top-8 by (d_bits, idx); idx scanned ascending so key-compare suffices
    unsigned kd[KC], ki[KC];
#pragma unroll
    for (int t = 0; t < KC; ++t) { kd[t] = 0xFFFFFFFFu; ki[t] = 0xFFFFFFFFu; }

    for (int j0 = 0; j0 < NGT / 64; ++j0) {
      int j = j0 * 64 + lane;  // lane-consecutive -> conflict-free LDS; disjoint idx per lane
      unsigned key = dist_bits(px, py, pz, sx[j], sy[j], sz[j]);
      if (key < kd[KC - 1]) {
        // static-index insertion (no dynamic register indexing -> no scratch)
#pragma unroll
        for (int t = KC - 1; t >= 1; --t) {
          bool a = key < kd[t];
          bool b = key < kd[t - 1];
          if (a) {
            if (b) { kd[t] = kd[t - 1]; ki[t] = ki[t - 1]; }
            else   { kd[t] = key;       ki[t] = (unsigned)j; }
          }
        }
        if (key < kd[0]) { kd[0] = key; ki[0] = (unsigned)j; }
      }
    }

    // cross-lane merge: extract the 8 lex-smallest (idx unique across lanes)
    unsigned resd = 0, resi = 0;
#pragma unroll
    for (int r = 0; r < KC; ++r) {
      unsigned long long head = ((unsigned long long)kd[0] << 32) | (unsigned long long)ki[0];
      unsigned long long m = wave_min64(head);
      if (head == m) {  // unique owner pops its head
#pragma unroll
        for (int t = 0; t < KC - 1; ++t) { kd[t] = kd[t + 1]; ki[t] = ki[t + 1]; }
        kd[KC - 1] = 0xFFFFFFFFu; ki[KC - 1] = 0xFFFFFFFFu;
      }
      if (lane == r) { resd = (unsigned)(m >> 32); resi = (unsigned)m; }
    }
    if (lane < KC) cand[row * KC + lane] = make_uint2(resd, resi);
  }
}

// ---------------- Kernel B: batched greedy with exact prefix-commit (1 wave) ----------------
// Per pass: 64 rows propose their first-available candidate. Claims (d<thresh) are
// deduplicated via LDS atomicMin; commit the prefix of lanes before the first
// {duplicate-claim | candidate-exhausted} event. Provably identical to the serial greedy:
// within a pass the only way lane L's proposal can be serially stale is an earlier lane
// claiming the same gt (detected), or an earlier bad lane (prefix-cut).
__global__ __launch_bounds__(64) void greedy_kernel(const uint2* __restrict__ cand,
                                                    const float* __restrict__ pred,
                                                    const float* __restrict__ gt,
                                                    unsigned* __restrict__ match) {
  __shared__ unsigned avail[NGT / 32];           // 1 KB bitmap
  __shared__ unsigned claim[NGT];                // 32 KB (reset after each use)
  __shared__ float sx[NGT], sy[NGT], sz[NGT];    // 96 KB for rare fallback
  const int lane = threadIdx.x;

  for (int w = lane; w < NGT / 32; w += 64) avail[w] = 0xFFFFFFFFu;
  for (int j = lane; j < NGT; j += 64) {
    claim[j] = 0xFFFFFFFFu;
    sx[j] = gt[j * 7 + 0];
    sy[j] = gt[j * 7 + 1];
    sz[j] = gt[j * 7 + 2];
  }
  __syncthreads();

  int base = 0;
  while (base < MROWS) {
    __syncthreads();
    const int nAct = (MROWS - base < 64) ? (MROWS - base) : 64;
    const int row = base + lane;
    const bool active = lane < nAct;

    // load this row's 8 candidates (64 B = 4x uint4)
    unsigned cd[KC], ci[KC];
    if (active) {
      const uint4* cr = (const uint4*)(cand + (size_t)row * KC);
#pragma unroll
      for (int q = 0; q < 4; ++q) {
        uint4 v = cr[q];
        cd[q * 2 + 0] = v.x; ci[q * 2 + 0] = v.y;
        cd[q * 2 + 1] = v.z; ci[q * 2 + 1] = v.w;
      }
    } else {
#pragma unroll
      for (int t = 0; t < KC; ++t) { cd[t] = 0xFFFFFFFFu; ci[t] = 0u; }
    }

    // availability mask of the 8 candidates (independent LDS reads)
    unsigned am = 0;
#pragma unroll
    for (int t = 0; t < KC; ++t) {
      unsigned g = ci[t];
      unsigned wd = avail[g >> 5];
      am |= ((wd >> (g & 31)) & 1u) << t;
    }
    if (!active) am = 0;

    // first available candidate, selected with static indexing only
    unsigned pd = 0xFFFFFFFFu, pg = 0u;
#pragma unroll
    for (int t = KC - 1; t >= 0; --t) {
      if (am & (1u << t)) { pd = cd[t]; pg = ci[t]; }
    }
    const bool found = am != 0u;
    const bool claimer = active && found && (pd < THRESH_BITS);

    if (claimer) atomicMin(&claim[pg], (unsigned)lane);
    __syncthreads();

    bool conflict = false;
    if (claimer) conflict = claim[pg] < (unsigned)lane;
    const bool bad = active && (!found || conflict);

    unsigned long long bbal = __ballot(bad);
    int firstBad = bbal ? (__ffsll((unsigned long long)bbal) - 1) : 64;
    int commitCount = firstBad < nAct ? firstBad : nAct;

    // reset claim slots (wave-lockstep: every lane's read above precedes this write)
    if (claimer) claim[pg] = 0xFFFFFFFFu;

    if (active && lane < commitCount) {
      match[row] = (claimer ? 0x80000000u : 0u) | pg;
      if (claimer) atomicAnd(&avail[pg >> 5], ~(1u << (pg & 31)));
    }
    base += commitCount;

    if (firstBad < nAct) {
      unsigned long long fbal = __ballot(active && !found);
      bool isFall = (fbal >> firstBad) & 1ull;
      if (isFall) {
        // candidate list exhausted: exact masked argmin over all gts (rare)
        __syncthreads();
        const int r = base;  // == row index of the fallback lane
        float px = pred[(size_t)r * 7 + 0];
        float py = pred[(size_t)r * 7 + 1];
        float pz = pred[(size_t)r * 7 + 2];
        unsigned long long best = ~0ull;
        for (int j0 = 0; j0 < NGT / 64; ++j0) {
          int j = j0 * 64 + lane;
          unsigned wd = avail[j >> 5];
          if ((wd >> (j & 31)) & 1u) {
            unsigned db = dist_bits(px, py, pz, sx[j], sy[j], sz[j]);
            unsigned long long key = ((unsigned long long)db << 32) | (unsigned)j;
            if (key < best) best = key;
          }
        }
        unsigned long long m = wave_min64(best);
        if (lane == 0) {
          if (m == ~0ull) {
            match[r] = 0u;  // nothing available anywhere -> unmatched, idx 0 (matches argmin-of-inf)
          } else {
            unsigned db = (unsigned)(m >> 32);
            unsigned j = (unsigned)m;
            bool ok = db < THRESH_BITS;
            if (ok) atomicAnd(&avail[j >> 5], ~(1u << (j & 31)));
            match[r] = (ok ? 0x80000000u : 0u) | j;
          }
        }
        base += 1;
      }
      // conflict case: blocked lane re-proposes next pass as lane 0 (cannot conflict) -> progress
    }
  }
}

// ---------------- Kernel C: loss terms + reduction ----------------
__device__ __forceinline__ float smooth_l1(float x) {
  float a = fabsf(x);
  return (a < 1.0f) ? (0.5f * a * a) : (a - 0.5f);
}

__global__ __launch_bounds__(256) void loss_kernel(const float* __restrict__ pred,
                                                   const float* __restrict__ gt,
                                                   const unsigned* __restrict__ match,
                                                   float* __restrict__ acc) {
  int i = blockIdx.x * 256 + threadIdx.x;
  float vc = 0.f, vs = 0.f, vo = 0.f, vi = 0.f, vk = 0.f;
  if (i < MROWS) {
    unsigned r = match[i];
    if (r & 0x80000000u) {
      unsigned j = r & 0x7FFFFFFFu;
      float p[7], g[7];
#pragma unroll
      for (int t = 0; t < 7; ++t) { p[t] = pred[i * 7 + t]; g[t] = gt[j * 7 + t]; }
      vc = smooth_l1(p[0] - g[0]) + smooth_l1(p[1] - g[1]) + smooth_l1(p[2] - g[2]);
      vs = smooth_l1(p[3] - g[3]) + smooth_l1(p[4] - g[4]) + smooth_l1(p[5] - g[5]);
      float d = p[6] - g[6];
      // atan2(sin d, cos d) == wrap to [-pi, pi]; smooth_l1 is even so boundary sign is moot
      float w = d - 6.283185307179586f * rintf(d * 0.15915494309189535f);
      vo = smooth_l1(w);
      float iw = fminf(p[0] + p[3] * 0.5f, g[0] + g[3] * 0.5f) -
                 fmaxf(p[0] - p[3] * 0.5f, g[0] - g[3] * 0.5f);
      iw = fmaxf(iw, 0.0f);
      float ih = fminf(p[1] + p[4] * 0.5f, g[1] + g[4] * 0.5f) -
                 fmaxf(p[1] - p[4] * 0.5f, g[1] - g[4] * 0.5f);
      ih = fmaxf(ih, 0.0f);
      float inter = iw * ih;
      float uni = p[3] * p[4] + g[3] * g[4] - inter;
      vi = 1.0f - inter / (uni + 1e-6f);
      vk = 1.0f;
    }
  }
#pragma unroll
  for (int off = 32; off >= 1; off >>= 1) {
    vc += __shfl_down(vc, off, 64);
    vs += __shfl_down(vs, off, 64);
    vo += __shfl_down(vo, off, 64);
    vi += __shfl_down(vi, off, 64);
    vk += __shfl_down(vk, off, 64);
  }
  if ((threadIdx.x & 63) == 0) {
    atomicAdd(&acc[0], vc);
    atomicAdd(&acc[1], vs);
    atomicAdd(&acc[2], vo);
    atomicAdd(&acc[3], vi);
    atomicAdd(&acc[4], vk);
  }
}

__global__ void finalize_kernel(const float* __restrict__ acc, float* __restrict__ out) {
  float k = fmaxf(acc[4], 1.0f);
  float loss = acc[0] / (3.0f * k)
             + 0.5f * (acc[1] / (3.0f * k) + acc[2] / k)
             + 2.0f * (acc[3] / k);
  out[0] = loss;
}

extern "C" void kernel_launch(void* const* d_in, const int* in_sizes, int n_in,
                              void* d_out, int out_size, void* d_ws, size_t ws_size,
                              hipStream_t stream) {
  const float* pred = (const float*)d_in[0];
  const float* gt   = (const float*)d_in[1];
  char* ws = (char*)d_ws;
  float* acc       = (float*)ws;                    // 32 B accumulators
  unsigned* match  = (unsigned*)(ws + 1024);        // 32 KB
  uint2* cand      = (uint2*)(ws + 1024 + 32768);   // 512 KB

  hipMemsetAsync(acc, 0, 32, stream);
  topk_kernel<<<256, 256, 0, stream>>>(pred, gt, cand);
  greedy_kernel<<<1, 64, 0, stream>>>(cand, pred, gt, match);
  loss_kernel<<<MROWS / 256, 256, 0, stream>>>(pred, gt, match, acc);
  finalize_kernel<<<1, 1, 0, stream>>>(acc, (float*)d_out);
}

// Round 6
// 292.460 us; speedup vs baseline: 2.0764x; 2.0764x over previous
//
#include <hip/hip_runtime.h>
#include <stdint.h>

#define MROWS 8192
#define NGT   8192
#define KC    8
#define RPW   4                    // rows per wave in topk
#define THRESH_BITS 0x40A00000u    // __float_as_uint(5.0f)

// Exact same fp32 ops/association as numpy: diff, square, left-to-right sum, IEEE sqrt.
// No FMA contraction so comparisons are bit-identical to the reference.
__device__ __forceinline__ unsigned dist_bits(float px, float py, float pz,
                                              float gx, float gy, float gz) {
#pragma clang fp contract(off)
  float dx = px - gx;
  float dy = py - gy;
  float dz = pz - gz;
  float s = (dx * dx + dy * dy) + dz * dz;
  return __float_as_uint(sqrtf(s));  // d >= 0, bits order == float order
}

__device__ __forceinline__ unsigned long long wave_min64(unsigned long long v) {
#pragma unroll
  for (int off = 32; off >= 1; off >>= 1) {
    unsigned long long o = __shfl_xor(v, off, 64);
    v = (o < v) ? o : v;
  }
  return v;
}

// ---------------- Kernel 0: pack gt centers into L2-resident float4 SoA ----------------
__global__ __launch_bounds__(256) void pack_kernel(const float* __restrict__ gt,
                                                   float4* __restrict__ cen) {
  int j = blockIdx.x * 256 + threadIdx.x;
  if (j < NGT) cen[j] = make_float4(gt[j * 7 + 0], gt[j * 7 + 1], gt[j * 7 + 2], 0.0f);
}

// ---------------- Kernel A: exact top-8 (d_bits, idx) lex-smallest per row ----------------
// No LDS: centers stream from L2 (128 KB resident). 4 rows/wave amortize each
// coalesced float4 load over 4 distance evals; occupancy capped only by VGPRs.
__global__ __launch_bounds__(256, 4) void topk_kernel(const float* __restrict__ pred,
                                                      const float4* __restrict__ cen,
                                                      uint2* __restrict__ cand) {
  const int tid = threadIdx.x;
  const int lane = tid & 63;
  const int wave = (blockIdx.x * 256 + tid) >> 6;  // 0..2047 at grid=512
  const int r0 = wave * RPW;

  float px[RPW], py[RPW], pz[RPW];
#pragma unroll
  for (int r = 0; r < RPW; ++r) {
    px[r] = pred[(size_t)(r0 + r) * 7 + 0];
    py[r] = pred[(size_t)(r0 + r) * 7 + 1];
    pz[r] = pred[(size_t)(r0 + r) * 7 + 2];
  }

  // per-lane sorted top-8 by (d_bits, idx) per row; idx scanned ascending
  unsigned kd[RPW][KC], ki[RPW][KC];
#pragma unroll
  for (int r = 0; r < RPW; ++r)
#pragma unroll
    for (int t = 0; t < KC; ++t) { kd[r][t] = 0xFFFFFFFFu; ki[r][t] = 0xFFFFFFFFu; }

#pragma unroll 2
  for (int j0 = 0; j0 < NGT / 64; ++j0) {
    int j = j0 * 64 + lane;            // coalesced: lane-consecutive, disjoint idx per lane
    float4 c = cen[j];
#pragma unroll
    for (int r = 0; r < RPW; ++r) {
      unsigned key = dist_bits(px[r], py[r], pz[r], c.x, c.y, c.z);
      if (key < kd[r][KC - 1]) {
        // static-index insertion (no dynamic register indexing -> no scratch)
#pragma unroll
        for (int t = KC - 1; t >= 1; --t) {
          bool a = key < kd[r][t];
          bool b = key < kd[r][t - 1];
          if (a) {
            if (b) { kd[r][t] = kd[r][t - 1]; ki[r][t] = ki[r][t - 1]; }
            else   { kd[r][t] = key;          ki[r][t] = (unsigned)j; }
          }
        }
        if (key < kd[r][0]) { kd[r][0] = key; ki[r][0] = (unsigned)j; }
      }
    }
  }

  // cross-lane merge per row: extract the 8 lex-smallest (idx unique across lanes)
#pragma unroll
  for (int r = 0; r < RPW; ++r) {
    unsigned resd = 0, resi = 0;
#pragma unroll
    for (int rr = 0; rr < KC; ++rr) {
      unsigned long long head = ((unsigned long long)kd[r][0] << 32) | (unsigned long long)ki[r][0];
      unsigned long long m = wave_min64(head);
      if (head == m) {  // unique owner pops its head
#pragma unroll
        for (int t = 0; t < KC - 1; ++t) { kd[r][t] = kd[r][t + 1]; ki[r][t] = ki[r][t + 1]; }
        kd[r][KC - 1] = 0xFFFFFFFFu; ki[r][KC - 1] = 0xFFFFFFFFu;
      }
      if (lane == rr) { resd = (unsigned)(m >> 32); resi = (unsigned)m; }
    }
    if (lane < KC) cand[(size_t)(r0 + r) * KC + lane] = make_uint2(resd, resi);
  }
}

__device__ __forceinline__ void load_cand_row(const uint2* __restrict__ cand, int row,
                                              unsigned (&dd)[KC], unsigned (&ii)[KC]) {
  const uint4* cr = (const uint4*)(cand + (size_t)row * KC);
#pragma unroll
  for (int q = 0; q < 4; ++q) {
    uint4 v = cr[q];
    dd[q * 2 + 0] = v.x; ii[q * 2 + 0] = v.y;
    dd[q * 2 + 1] = v.z; ii[q * 2 + 1] = v.w;
  }
}

// ---------------- Kernel B: batched greedy, in-pass conflict resolution (1 wave) ------
// Per pass of 64 rows: iterate {propose first remaining candidate -> atomicMin claim ->
// losers advance} to a fixed point. Claims are monotone (a claimed gt stays claimed by
// that lane or a smaller one), so the fixed point equals the serial greedy by induction
// on lane order. Cut only at the first truly-exhausted row (full-scan fallback, exact).
__global__ __launch_bounds__(64) void greedy_kernel(const uint2* __restrict__ cand,
                                                    const float* __restrict__ pred,
                                                    const float* __restrict__ gt,
                                                    unsigned* __restrict__ match) {
  __shared__ unsigned avail[NGT / 32];           // 1 KB bitmap
  __shared__ unsigned claim[NGT];                // 32 KB (reset after each pass)
  __shared__ float sx[NGT], sy[NGT], sz[NGT];    // 96 KB for rare fallback
  const int lane = threadIdx.x;

  for (int w = lane; w < NGT / 32; w += 64) avail[w] = 0xFFFFFFFFu;
  for (int j = lane; j < NGT; j += 64) {
    claim[j] = 0xFFFFFFFFu;
    sx[j] = gt[j * 7 + 0];
    sy[j] = gt[j * 7 + 1];
    sz[j] = gt[j * 7 + 2];
  }
  __syncthreads();

  unsigned cd[KC], ci[KC], nd[KC], ni[KC];
  int prefBase = -1;

  int base = 0;
  while (base < MROWS) {
    const int nAct = (MROWS - base < 64) ? (MROWS - base) : 64;
    const int row = base + lane;
    const bool active = lane < nAct;

    if (base == prefBase) {
#pragma unroll
      for (int t = 0; t < KC; ++t) { cd[t] = nd[t]; ci[t] = ni[t]; }
    } else {
      load_cand_row(cand, active ? row : (MROWS - 1), cd, ci);
    }
    // prefetch predicted next pass (full commit); resolution below hides the latency
    prefBase = base + nAct;
    {
      int pr = prefBase + lane;
      if (pr >= MROWS) pr = MROWS - 1;
      load_cand_row(cand, pr, nd, ni);
    }

    // remaining-candidate mask vs avail at pass start
    unsigned m = 0;
#pragma unroll
    for (int t = 0; t < KC; ++t) {
      unsigned g = ci[t];
      m |= ((avail[g >> 5] >> (g & 31)) & 1u) << t;
    }
    if (!active) m = 0;

    // fixed-point resolution (wave-lockstep; LDS same-array deps ordered by compiler)
    unsigned pd = 0xFFFFFFFFu, pg = 0u;
    bool isClaim = false;
    bool forceSerial = false;
    int guard = 0;
    while (true) {
      pd = 0xFFFFFFFFu; pg = 0u;
#pragma unroll
      for (int t = KC - 1; t >= 0; --t)
        if (m & (1u << t)) { pd = cd[t]; pg = ci[t]; }
      isClaim = active && (m != 0u) && (pd < THRESH_BITS);
      if (isClaim) atomicMin(&claim[pg], (unsigned)lane);
      __builtin_amdgcn_wave_barrier();
      bool lost = isClaim && (claim[pg] < (unsigned)lane);
      unsigned long long adv = __ballot(lost);
      if (adv == 0ull) break;          // stable: every claimer owns its gt
      if (lost) m &= (m - 1u);         // drop lowest (stolen) candidate, re-propose
      if (++guard > 600) { forceSerial = true; break; }  // unreachable; exact safety
    }

    unsigned long long exb = __ballot(active && (m == 0u));
    int firstExh = exb ? (__ffsll(exb) - 1) : 64;
    if (forceSerial) firstExh = 0;
    int commitCount = firstExh < nAct ? firstExh : nAct;

    if (active && lane < commitCount) {
      match[row] = (isClaim ? 0x80000000u : 0u) | pg;
      if (isClaim) atomicAnd(&avail[pg >> 5], ~(1u << (pg & 31)));
    }
    // reset every claim slot we may have touched (write-only, value idempotent)
#pragma unroll
    for (int t = 0; t < KC; ++t) claim[ci[t]] = 0xFFFFFFFFu;
    __builtin_amdgcn_wave_barrier();

    base += commitCount;

    if (commitCount < nAct) {
      // row 'base': top-8 exhausted (or safety) -> exact full-scan argmin over avail
      const int r = base;
      float fx = pred[(size_t)r * 7 + 0];
      float fy = pred[(size_t)r * 7 + 1];
      float fz = pred[(size_t)r * 7 + 2];
      unsigned long long best = ~0ull;
      for (int j0 = 0; j0 < NGT / 64; ++j0) {
        int j = j0 * 64 + lane;
        if ((avail[j >> 5] >> (j & 31)) & 1u) {
          unsigned db = dist_bits(fx, fy, fz, sx[j], sy[j], sz[j]);
          unsigned long long key = ((unsigned long long)db << 32) | (unsigned)j;
          if (key < best) best = key;
        }
      }
      unsigned long long mm = wave_min64(best);
      if (lane == 0) {
        if (mm == ~0ull) {
          match[r] = 0u;  // nothing available -> unmatched (masked; idx irrelevant)
        } else {
          unsigned db = (unsigned)(mm >> 32);
          unsigned j = (unsigned)mm;
          bool ok = db < THRESH_BITS;
          if (ok) atomicAnd(&avail[j >> 5], ~(1u << (j & 31)));
          match[r] = (ok ? 0x80000000u : 0u) | j;
        }
      }
      __builtin_amdgcn_wave_barrier();
      base += 1;
    }
  }
}

// ---------------- Kernel C: loss terms + reduction ----------------
__device__ __forceinline__ float smooth_l1(float x) {
  float a = fabsf(x);
  return (a < 1.0f) ? (0.5f * a * a) : (a - 0.5f);
}

__global__ __launch_bounds__(256) void loss_kernel(const float* __restrict__ pred,
                                                   const float* __restrict__ gt,
                                                   const unsigned* __restrict__ match,
                                                   float* __restrict__ acc) {
  int i = blockIdx.x * 256 + threadIdx.x;
  float vc = 0.f, vs = 0.f, vo = 0.f, vi = 0.f, vk = 0.f;
  if (i < MROWS) {
    unsigned r = match[i];
    if (r & 0x80000000u) {
      unsigned j = r & 0x7FFFFFFFu;
      float p[7], g[7];
#pragma unroll
      for (int t = 0; t < 7; ++t) { p[t] = pred[i * 7 + t]; g[t] = gt[j * 7 + t]; }
      vc = smooth_l1(p[0] - g[0]) + smooth_l1(p[1] - g[1]) + smooth_l1(p[2] - g[2]);
      vs = smooth_l1(p[3] - g[3]) + smooth_l1(p[4] - g[4]) + smooth_l1(p[5] - g[5]);
      float d = p[6] - g[6];
      // atan2(sin d, cos d) == wrap to [-pi, pi]; smooth_l1 is even so boundary sign is moot
      float w = d - 6.283185307179586f * rintf(d * 0.15915494309189535f);
      vo = smooth_l1(w);
      float iw = fminf(p[0] + p[3] * 0.5f, g[0] + g[3] * 0.5f) -
                 fmaxf(p[0] - p[3] * 0.5f, g[0] - g[3] * 0.5f);
      iw = fmaxf(iw, 0.0f);
      float ih = fminf(p[1] + p[4] * 0.5f, g[1] + g[4] * 0.5f) -
                 fmaxf(p[1] - p[4] * 0.5f, g[1] - g[4] * 0.5f);
      ih = fmaxf(ih, 0.0f);
      float inter = iw * ih;
      float uni = p[3] * p[4] + g[3] * g[4] - inter;
      vi = 1.0f - inter / (uni + 1e-6f);
      vk = 1.0f;
    }
  }
#pragma unroll
  for (int off = 32; off >= 1; off >>= 1) {
    vc += __shfl_down(vc, off, 64);
    vs += __shfl_down(vs, off, 64);
    vo += __shfl_down(vo, off, 64);
    vi += __shfl_down(vi, off, 64);
    vk += __shfl_down(vk, off, 64);
  }
  if ((threadIdx.x & 63) == 0) {
    atomicAdd(&acc[0], vc);
    atomicAdd(&acc[1], vs);
    atomicAdd(&acc[2], vo);
    atomicAdd(&acc[3], vi);
    atomicAdd(&acc[4], vk);
  }
}

__global__ void finalize_kernel(const float* __restrict__ acc, float* __restrict__ out) {
  float k = fmaxf(acc[4], 1.0f);
  float loss = acc[0] / (3.0f * k)
             + 0.5f * (acc[1] / (3.0f * k) + acc[2] / k)
             + 2.0f * (acc[3] / k);
  out[0] = loss;
}

extern "C" void kernel_launch(void* const* d_in, const int* in_sizes, int n_in,
                              void* d_out, int out_size, void* d_ws, size_t ws_size,
                              hipStream_t stream) {
  const float* pred = (const float*)d_in[0];
  const float* gt   = (const float*)d_in[1];
  char* ws = (char*)d_ws;
  float* acc       = (float*)ws;                        // 32 B accumulators
  unsigned* match  = (unsigned*)(ws + 1024);            // 32 KB
  uint2* cand      = (uint2*)(ws + 33792);              // 512 KB
  float4* cen      = (float4*)(ws + 558080);            // 128 KB packed centers

  hipMemsetAsync(acc, 0, 32, stream);
  pack_kernel<<<NGT / 256, 256, 0, stream>>>(gt, cen);
  topk_kernel<<<MROWS / (RPW * 4), 256, 0, stream>>>(pred, cen, cand);
  greedy_kernel<<<1, 64, 0, stream>>>(cand, pred, gt, match);
  loss_kernel<<<MROWS / 256, 256, 0, stream>>>(pred, gt, match, acc);
  finalize_kernel<<<1, 1, 0, stream>>>(acc, (float*)d_out);
}

// Round 8
// 236.285 us; speedup vs baseline: 2.5701x; 1.2377x over previous
//
#include <hip/hip_runtime.h>
#include <stdint.h>

#define MROWS 8192
#define NGT   8192
#define KC    8                    // global top-K per row (candidates for greedy)
#define KL    4                    // per-lane kept in fast path (verified-exact)
#define RPW   2                    // rows per wave in topk
#define THRESH_BITS 0x40A00000u    // __float_as_uint(5.0f)

// Exact same fp32 ops/association as numpy: diff, square, left-to-right sum, IEEE sqrt.
// No FMA contraction so comparisons are bit-identical to the reference.
__device__ __forceinline__ unsigned dist_bits(float px, float py, float pz,
                                              float gx, float gy, float gz) {
#pragma clang fp contract(off)
  float dx = px - gx;
  float dy = py - gy;
  float dz = pz - gz;
  float s = (dx * dx + dy * dy) + dz * dz;
  return __float_as_uint(sqrtf(s));  // d >= 0, bits order == float order
}

__device__ __forceinline__ unsigned long long wave_min64(unsigned long long v) {
#pragma unroll
  for (int off = 32; off >= 1; off >>= 1) {
    unsigned long long o = __shfl_xor(v, off, 64);
    v = (o < v) ? o : v;
  }
  return v;
}

template <int K>
__device__ __forceinline__ void insert_sorted(unsigned (&kd)[K], unsigned (&ki)[K],
                                              unsigned key, unsigned j) {
  // static-index insertion (no dynamic register indexing -> no scratch)
#pragma unroll
  for (int t = K - 1; t >= 1; --t) {
    bool a = key < kd[t];
    bool b = key < kd[t - 1];
    if (a) {
      if (b) { kd[t] = kd[t - 1]; ki[t] = ki[t - 1]; }
      else   { kd[t] = key;       ki[t] = j; }
    }
  }
  if (key < kd[0]) { kd[0] = key; ki[0] = j; }
}

// Extract the 8 lex-smallest (d,idx) keys from the union of per-lane sorted lists.
// Returns lane r holding the r-th smallest in (resd,resi); e8 = 8th smallest key (all lanes).
template <int K>
__device__ __forceinline__ void extract8(unsigned (&kd)[K], unsigned (&ki)[K], int lane,
                                         unsigned& resd, unsigned& resi,
                                         unsigned long long& e8) {
#pragma unroll
  for (int rr = 0; rr < KC; ++rr) {
    unsigned long long head = ((unsigned long long)kd[0] << 32) | (unsigned long long)ki[0];
    unsigned long long m = wave_min64(head);
    if (head == m) {  // unique owner (idx unique) pops its head
#pragma unroll
      for (int t = 0; t < K - 1; ++t) { kd[t] = kd[t + 1]; ki[t] = ki[t + 1]; }
      kd[K - 1] = 0xFFFFFFFFu; ki[K - 1] = 0xFFFFFFFFu;
    }
    if (lane == rr) { resd = (unsigned)(m >> 32); resi = (unsigned)m; }
    e8 = m;
  }
}

// ---------------- Kernel 0: pack gt centers into L2-resident float4 SoA ----------------
__global__ __launch_bounds__(256) void pack_kernel(const float* __restrict__ gt,
                                                   float4* __restrict__ cen) {
  int j = blockIdx.x * 256 + threadIdx.x;
  if (j < NGT) cen[j] = make_float4(gt[j * 7 + 0], gt[j * 7 + 1], gt[j * 7 + 2], 0.0f);
}

// ---------------- Kernel A: exact top-8 (d_bits, idx) lex-smallest per row ----------------
// Fast path: per-lane top-4, merged to global top-8 with an exactness certificate:
// every discarded key >= the lane's final kd[KL-1] (it only decreases), so if all lanes'
// kd[KL-1] >= e8 (the extracted 8th-smallest), nothing in the top-8 was discarded.
// Rare unsafe rows (~1e-4) recompute with per-lane top-8 (unconditionally exact).
__global__ __launch_bounds__(256, 4) void topk_kernel(const float* __restrict__ pred,
                                                      const float4* __restrict__ cen,
                                                      uint2* __restrict__ cand) {
  const int tid = threadIdx.x;
  const int lane = tid & 63;
  const int wave = (blockIdx.x * 256 + tid) >> 6;  // 0..4095 at grid=1024
  const int r0 = wave * RPW;

  float px[RPW], py[RPW], pz[RPW];
#pragma unroll
  for (int r = 0; r < RPW; ++r) {
    px[r] = pred[(size_t)(r0 + r) * 7 + 0];
    py[r] = pred[(size_t)(r0 + r) * 7 + 1];
    pz[r] = pred[(size_t)(r0 + r) * 7 + 2];
  }

  unsigned kd[RPW][KL], ki[RPW][KL];
#pragma unroll
  for (int r = 0; r < RPW; ++r)
#pragma unroll
    for (int t = 0; t < KL; ++t) { kd[r][t] = 0xFFFFFFFFu; ki[r][t] = 0xFFFFFFFFu; }

#pragma unroll 2
  for (int j0 = 0; j0 < NGT / 64; ++j0) {
    int j = j0 * 64 + lane;            // coalesced; disjoint idx per lane
    float4 c = cen[j];
#pragma unroll
    for (int r = 0; r < RPW; ++r) {
      unsigned key = dist_bits(px[r], py[r], pz[r], c.x, c.y, c.z);
      if (key < kd[r][KL - 1]) insert_sorted<KL>(kd[r], ki[r], key, (unsigned)j);
    }
  }

#pragma unroll
  for (int r = 0; r < RPW; ++r) {
    const int row = r0 + r;
    // certificate guard: lane's worst kept key (discards are all >= this)
    unsigned long long guard =
        ((unsigned long long)kd[r][KL - 1] << 32) | (unsigned long long)ki[r][KL - 1];
    unsigned resd = 0, resi = 0;
    unsigned long long e8 = 0;
    extract8<KL>(kd[r], ki[r], lane, resd, resi, e8);

    if (__ballot(guard < e8) != 0ull) {
      // unsafe: a lane may have discarded a true top-8 member -> exact recompute
      unsigned fd[KC], fi[KC];
#pragma unroll
      for (int t = 0; t < KC; ++t) { fd[t] = 0xFFFFFFFFu; fi[t] = 0xFFFFFFFFu; }
      for (int j0 = 0; j0 < NGT / 64; ++j0) {
        int j = j0 * 64 + lane;
        float4 c = cen[j];
        unsigned key = dist_bits(px[r], py[r], pz[r], c.x, c.y, c.z);
        if (key < fd[KC - 1]) insert_sorted<KC>(fd, fi, key, (unsigned)j);
      }
      unsigned long long dummy;
      extract8<KC>(fd, fi, lane, resd, resi, dummy);
    }
    if (lane < KC) cand[(size_t)row * KC + lane] = make_uint2(resd, resi);
  }
}

__device__ __forceinline__ void load_cand_row(const uint2* __restrict__ cand, int row,
                                              unsigned (&dd)[KC], unsigned (&ii)[KC]) {
  const uint4* cr = (const uint4*)(cand + (size_t)row * KC);
#pragma unroll
  for (int q = 0; q < 4; ++q) {
    uint4 v = cr[q];
    dd[q * 2 + 0] = v.x; ii[q * 2 + 0] = v.y;
    dd[q * 2 + 1] = v.z; ii[q * 2 + 1] = v.w;
  }
}

// ---------------- Kernel B: batched greedy, in-pass conflict resolution (1 wave) ------
// Per pass of 64 rows: iterate {propose first remaining candidate -> atomicMin claim ->
// losers advance} to a fixed point. Claims are monotone (a claimed gt stays claimed by
// that lane or a smaller one), so the fixed point equals the serial greedy by induction
// on lane order. Cut only at the first truly-exhausted row (full-scan fallback, exact).
__global__ __launch_bounds__(64) void greedy_kernel(const uint2* __restrict__ cand,
                                                    const float* __restrict__ pred,
                                                    const float* __restrict__ gt,
                                                    unsigned* __restrict__ match) {
  __shared__ unsigned avail[NGT / 32];           // 1 KB bitmap
  __shared__ unsigned claim[NGT];                // 32 KB (reset after each pass)
  __shared__ float sx[NGT], sy[NGT], sz[NGT];    // 96 KB for rare fallback
  const int lane = threadIdx.x;

  for (int w = lane; w < NGT / 32; w += 64) avail[w] = 0xFFFFFFFFu;
  for (int j = lane; j < NGT; j += 64) {
    claim[j] = 0xFFFFFFFFu;
    sx[j] = gt[j * 7 + 0];
    sy[j] = gt[j * 7 + 1];
    sz[j] = gt[j * 7 + 2];
  }
  __syncthreads();

  unsigned cd[KC], ci[KC], nd[KC], ni[KC];
  int prefBase = -1;

  int base = 0;
  while (base < MROWS) {
    const int nAct = (MROWS - base < 64) ? (MROWS - base) : 64;
    const int row = base + lane;
    const bool active = lane < nAct;

    if (base == prefBase) {
#pragma unroll
      for (int t = 0; t < KC; ++t) { cd[t] = nd[t]; ci[t] = ni[t]; }
    } else {
      load_cand_row(cand, active ? row : (MROWS - 1), cd, ci);
    }
    // prefetch predicted next pass (full commit); resolution below hides the latency
    prefBase = base + nAct;
    {
      int pr = prefBase + lane;
      if (pr >= MROWS) pr = MROWS - 1;
      load_cand_row(cand, pr, nd, ni);
    }

    // remaining-candidate mask vs avail at pass start
    unsigned m = 0;
#pragma unroll
    for (int t = 0; t < KC; ++t) {
      unsigned g = ci[t];
      m |= ((avail[g >> 5] >> (g & 31)) & 1u) << t;
    }
    if (!active) m = 0;

    // fixed-point resolution (wave-lockstep; LDS same-array deps ordered by compiler)
    unsigned pd = 0xFFFFFFFFu, pg = 0u;
    bool isClaim = false;
    bool forceSerial = false;
    int guard = 0;
    while (true) {
      pd = 0xFFFFFFFFu; pg = 0u;
#pragma unroll
      for (int t = KC - 1; t >= 0; --t)
        if (m & (1u << t)) { pd = cd[t]; pg = ci[t]; }
      isClaim = active && (m != 0u) && (pd < THRESH_BITS);
      if (isClaim) atomicMin(&claim[pg], (unsigned)lane);
      __builtin_amdgcn_wave_barrier();
      bool lost = isClaim && (claim[pg] < (unsigned)lane);
      unsigned long long adv = __ballot(lost);
      if (adv == 0ull) break;          // stable: every claimer owns its gt
      if (lost) m &= (m - 1u);         // drop lowest (stolen) candidate, re-propose
      if (++guard > 600) { forceSerial = true; break; }  // unreachable; exact safety
    }

    unsigned long long exb = __ballot(active && (m == 0u));
    int firstExh = exb ? (__ffsll(exb) - 1) : 64;
    if (forceSerial) firstExh = 0;
    int commitCount = firstExh < nAct ? firstExh : nAct;

    if (active && lane < commitCount) {
      match[row] = (isClaim ? 0x80000000u : 0u) | pg;
      if (isClaim) atomicAnd(&avail[pg >> 5], ~(1u << (pg & 31)));
    }
    // reset every claim slot we may have touched (write-only, value idempotent)
#pragma unroll
    for (int t = 0; t < KC; ++t) claim[ci[t]] = 0xFFFFFFFFu;
    __builtin_amdgcn_wave_barrier();

    base += commitCount;

    if (commitCount < nAct) {
      // row 'base': top-8 exhausted (or safety) -> exact full-scan argmin over avail
      const int r = base;
      float fx = pred[(size_t)r * 7 + 0];
      float fy = pred[(size_t)r * 7 + 1];
      float fz = pred[(size_t)r * 7 + 2];
      unsigned long long best = ~0ull;
      for (int j0 = 0; j0 < NGT / 64; ++j0) {
        int j = j0 * 64 + lane;
        if ((avail[j >> 5] >> (j & 31)) & 1u) {
          unsigned db = dist_bits(fx, fy, fz, sx[j], sy[j], sz[j]);
          unsigned long long key = ((unsigned long long)db << 32) | (unsigned)j;
          if (key < best) best = key;
        }
      }
      unsigned long long mm = wave_min64(best);
      if (lane == 0) {
        if (mm == ~0ull) {
          match[r] = 0u;  // nothing available -> unmatched (masked; idx irrelevant)
        } else {
          unsigned db = (unsigned)(mm >> 32);
          unsigned j = (unsigned)mm;
          bool ok = db < THRESH_BITS;
          if (ok) atomicAnd(&avail[j >> 5], ~(1u << (j & 31)));
          match[r] = (ok ? 0x80000000u : 0u) | j;
        }
      }
      __builtin_amdgcn_wave_barrier();
      base += 1;
    }
  }
}

// ---------------- Kernel C: loss terms + reduction ----------------
__device__ __forceinline__ float smooth_l1(float x) {
  float a = fabsf(x);
  return (a < 1.0f) ? (0.5f * a * a) : (a - 0.5f);
}

__global__ __launch_bounds__(256) void loss_kernel(const float* __restrict__ pred,
                                                   const float* __restrict__ gt,
                                                   const unsigned* __restrict__ match,
                                                   float* __restrict__ acc) {
  int i = blockIdx.x * 256 + threadIdx.x;
  float vc = 0.f, vs = 0.f, vo = 0.f, vi = 0.f, vk = 0.f;
  if (i < MROWS) {
    unsigned r = match[i];
    if (r & 0x80000000u) {
      unsigned j = r & 0x7FFFFFFFu;
      float p[7], g[7];
#pragma unroll
      for (int t = 0; t < 7; ++t) { p[t] = pred[i * 7 + t]; g[t] = gt[j * 7 + t]; }
      vc = smooth_l1(p[0] - g[0]) + smooth_l1(p[1] - g[1]) + smooth_l1(p[2] - g[2]);
      vs = smooth_l1(p[3] - g[3]) + smooth_l1(p[4] - g[4]) + smooth_l1(p[5] - g[5]);
      float d = p[6] - g[6];
      // atan2(sin d, cos d) == wrap to [-pi, pi]; smooth_l1 is even so boundary sign is moot
      float w = d - 6.283185307179586f * rintf(d * 0.15915494309189535f);
      vo = smooth_l1(w);
      float iw = fminf(p[0] + p[3] * 0.5f, g[0] + g[3] * 0.5f) -
                 fmaxf(p[0] - p[3] * 0.5f, g[0] - g[3] * 0.5f);
      iw = fmaxf(iw, 0.0f);
      float ih = fminf(p[1] + p[4] * 0.5f, g[1] + g[4] * 0.5f) -
                 fmaxf(p[1] - p[4] * 0.5f, g[1] - g[4] * 0.5f);
      ih = fmaxf(ih, 0.0f);
      float inter = iw * ih;
      float uni = p[3] * p[4] + g[3] * g[4] - inter;
      vi = 1.0f - inter / (uni + 1e-6f);
      vk = 1.0f;
    }
  }
#pragma unroll
  for (int off = 32; off >= 1; off >>= 1) {
    vc += __shfl_down(vc, off, 64);
    vs += __shfl_down(vs, off, 64);
    vo += __shfl_down(vo, off, 64);
    vi += __shfl_down(vi, off, 64);
    vk += __shfl_down(vk, off, 64);
  }
  if ((threadIdx.x & 63) == 0) {
    atomicAdd(&acc[0], vc);
    atomicAdd(&acc[1], vs);
    atomicAdd(&acc[2], vo);
    atomicAdd(&acc[3], vi);
    atomicAdd(&acc[4], vk);
  }
}

__global__ void finalize_kernel(const float* __restrict__ acc, float* __restrict__ out) {
  float k = fmaxf(acc[4], 1.0f);
  float loss = acc[0] / (3.0f * k)
             + 0.5f * (acc[1] / (3.0f * k) + acc[2] / k)
             + 2.0f * (acc[3] / k);
  out[0] = loss;
}

extern "C" void kernel_launch(void* const* d_in, const int* in_sizes, int n_in,
                              void* d_out, int out_size, void* d_ws, size_t ws_size,
                              hipStream_t stream) {
  const float* pred = (const float*)d_in[0];
  const float* gt   = (const float*)d_in[1];
  char* ws = (char*)d_ws;
  float* acc       = (float*)ws;                        // 32 B accumulators
  unsigned* match  = (unsigned*)(ws + 1024);            // 32 KB
  uint2* cand      = (uint2*)(ws + 33792);              // 512 KB
  float4* cen      = (float4*)(ws + 558080);            // 128 KB packed centers

  hipMemsetAsync(acc, 0, 32, stream);
  pack_kernel<<<NGT / 256, 256, 0, stream>>>(gt, cen);
  topk_kernel<<<MROWS / (RPW * 4), 256, 0, stream>>>(pred, cen, cand);
  greedy_kernel<<<1, 64, 0, stream>>>(cand, pred, gt, match);
  loss_kernel<<<MROWS / 256, 256, 0, stream>>>(pred, gt, match, acc);
  finalize_kernel<<<1, 1, 0, stream>>>(acc, (float*)d_out);
}

// Round 9
// 214.932 us; speedup vs baseline: 2.8254x; 1.0993x over previous
//
#include <hip/hip_runtime.h>
#include <stdint.h>

#define MROWS 8192
#define NGT   8192
#define KC    8                    // global top-K per row (candidates for greedy)
#define KL    4                    // per-lane kept in fast path (verified-exact)
#define RPW   2                    // rows per wave in topk
#define RPL   4                    // rows per lane in greedy (256 rows/pass)
#define THRESH2_BITS 0x41C7FFFFu   // s_bits <  this  <=>  sqrt_rn(s) < 5.0f (exact)
#define THRESH_BITS  0x40A00000u   // __float_as_uint(5.0f), fallback d-space compare

// Squared distance, exact same fp32 ops/association as numpy pre-sqrt: diff, square,
// left-to-right sum. No FMA contraction. Ordering by (s,idx) == ordering by (d,idx)
// except on sqrt-rounding collisions (|gap| ~2^-24 relative at the min: prob ~0, and
// any affected row is either masked out or shifts the scalar loss by ~4e-4 << 2.6e-2).
__device__ __forceinline__ unsigned dist2_bits(float px, float py, float pz,
                                               float gx, float gy, float gz) {
#pragma clang fp contract(off)
  float dx = px - gx;
  float dy = py - gy;
  float dz = pz - gz;
  float s = (dx * dx + dy * dy) + dz * dz;
  return __float_as_uint(s);  // s >= 0, bits order == float order
}

__device__ __forceinline__ unsigned long long wave_min64(unsigned long long v) {
#pragma unroll
  for (int off = 32; off >= 1; off >>= 1) {
    unsigned long long o = __shfl_xor(v, off, 64);
    v = (o < v) ? o : v;
  }
  return v;
}

template <int K>
__device__ __forceinline__ void insert_sorted(unsigned (&kd)[K], unsigned (&ki)[K],
                                              unsigned key, unsigned j) {
  // static-index insertion (no dynamic register indexing -> no scratch)
#pragma unroll
  for (int t = K - 1; t >= 1; --t) {
    bool a = key < kd[t];
    bool b = key < kd[t - 1];
    if (a) {
      if (b) { kd[t] = kd[t - 1]; ki[t] = ki[t - 1]; }
      else   { kd[t] = key;       ki[t] = j; }
    }
  }
  if (key < kd[0]) { kd[0] = key; ki[0] = j; }
}

// Extract the 8 lex-smallest (s,idx) keys from the union of per-lane sorted lists.
// Lane r ends holding the r-th smallest in (resd,resi); e8 = 8th smallest (all lanes).
template <int K>
__device__ __forceinline__ void extract8(unsigned (&kd)[K], unsigned (&ki)[K], int lane,
                                         unsigned& resd, unsigned& resi,
                                         unsigned long long& e8) {
#pragma unroll
  for (int rr = 0; rr < KC; ++rr) {
    unsigned long long head = ((unsigned long long)kd[0] << 32) | (unsigned long long)ki[0];
    unsigned long long m = wave_min64(head);
    if (head == m) {  // unique owner (idx unique) pops its head
#pragma unroll
      for (int t = 0; t < K - 1; ++t) { kd[t] = kd[t + 1]; ki[t] = ki[t + 1]; }
      kd[K - 1] = 0xFFFFFFFFu; ki[K - 1] = 0xFFFFFFFFu;
    }
    if (lane == rr) { resd = (unsigned)(m >> 32); resi = (unsigned)m; }
    e8 = m;
  }
}

// ---------------- Kernel 0: pack gt centers into L2-resident float4 SoA ----------------
__global__ __launch_bounds__(256) void pack_kernel(const float* __restrict__ gt,
                                                   float4* __restrict__ cen) {
  int j = blockIdx.x * 256 + threadIdx.x;
  if (j < NGT) cen[j] = make_float4(gt[j * 7 + 0], gt[j * 7 + 1], gt[j * 7 + 2], 0.0f);
}

// ---------------- Kernel A: top-8 per row, emitted packed as (idx<<1)|claimable -------
// Fast path: per-lane top-4 + exactness certificate (all discards >= lane's final
// kd[KL-1]; if min-lane guard >= e8 nothing in the true top-8 was discarded).
// Unsafe rows (~1e-4) recompute with per-lane top-8.
__global__ __launch_bounds__(256, 4) void topk_kernel(const float* __restrict__ pred,
                                                      const float4* __restrict__ cen,
                                                      unsigned* __restrict__ cand) {
  const int tid = threadIdx.x;
  const int lane = tid & 63;
  const int wave = (blockIdx.x * 256 + tid) >> 6;  // 0..4095 at grid=1024
  const int r0 = wave * RPW;

  float px[RPW], py[RPW], pz[RPW];
#pragma unroll
  for (int r = 0; r < RPW; ++r) {
    px[r] = pred[(size_t)(r0 + r) * 7 + 0];
    py[r] = pred[(size_t)(r0 + r) * 7 + 1];
    pz[r] = pred[(size_t)(r0 + r) * 7 + 2];
  }

  unsigned kd[RPW][KL], ki[RPW][KL];
#pragma unroll
  for (int r = 0; r < RPW; ++r)
#pragma unroll
    for (int t = 0; t < KL; ++t) { kd[r][t] = 0xFFFFFFFFu; ki[r][t] = 0xFFFFFFFFu; }

#pragma unroll 2
  for (int j0 = 0; j0 < NGT / 64; ++j0) {
    int j = j0 * 64 + lane;            // coalesced; disjoint idx per lane
    float4 c = cen[j];
#pragma unroll
    for (int r = 0; r < RPW; ++r) {
      unsigned key = dist2_bits(px[r], py[r], pz[r], c.x, c.y, c.z);
      if (key < kd[r][KL - 1]) insert_sorted<KL>(kd[r], ki[r], key, (unsigned)j);
    }
  }

#pragma unroll
  for (int r = 0; r < RPW; ++r) {
    const int row = r0 + r;
    unsigned long long guard =
        ((unsigned long long)kd[r][KL - 1] << 32) | (unsigned long long)ki[r][KL - 1];
    unsigned resd = 0, resi = 0;
    unsigned long long e8 = 0;
    extract8<KL>(kd[r], ki[r], lane, resd, resi, e8);

    if (__ballot(guard < e8) != 0ull) {
      // unsafe: exact recompute with per-lane top-8
      unsigned fd[KC], fi[KC];
#pragma unroll
      for (int t = 0; t < KC; ++t) { fd[t] = 0xFFFFFFFFu; fi[t] = 0xFFFFFFFFu; }
      for (int j0 = 0; j0 < NGT / 64; ++j0) {
        int j = j0 * 64 + lane;
        float4 c = cen[j];
        unsigned key = dist2_bits(px[r], py[r], pz[r], c.x, c.y, c.z);
        if (key < fd[KC - 1]) insert_sorted<KC>(fd, fi, key, (unsigned)j);
      }
      unsigned long long dummy;
      extract8<KC>(fd, fi, lane, resd, resi, dummy);
    }
    // packed candidate: idx in bits 31..1, claimable (d<5.0, exact bit threshold) in bit 0
    if (lane < KC)
      cand[(size_t)row * KC + lane] = (resi << 1) | (resd < THRESH2_BITS ? 1u : 0u);
  }
}

// ---------------- Kernel B: batched greedy, 256 rows/pass, one wave -------------------
// Row offset o = lane + 64q is the claim priority. Fixed point of {propose first
// available candidate -> atomicMin claim -> losers drop it} equals the serial greedy
// by induction on row order (claims monotone; drops only to strictly-earlier rows).
// Cut at first truly-exhausted row -> exact full-scan fallback (sqrt space, bit-exact).
__global__ __launch_bounds__(64) void greedy_kernel(const unsigned* __restrict__ cand,
                                                    const float* __restrict__ pred,
                                                    const float* __restrict__ gt,
                                                    unsigned* __restrict__ match) {
  __shared__ unsigned avail[NGT / 32];           // 1 KB bitmap
  __shared__ unsigned claim[NGT];                // 32 KB (reset after each pass)
  __shared__ float sx[NGT], sy[NGT], sz[NGT];    // 96 KB for rare fallback
  const int lane = threadIdx.x;

  for (int w = lane; w < NGT / 32; w += 64) avail[w] = 0xFFFFFFFFu;
  for (int j = lane; j < NGT; j += 64) {
    claim[j] = 0xFFFFFFFFu;
    sx[j] = gt[j * 7 + 0];
    sy[j] = gt[j * 7 + 1];
    sz[j] = gt[j * 7 + 2];
  }
  __syncthreads();

  unsigned ci_[RPL][KC], ni_[RPL][KC];
  int prefBase = -1;

  int base = 0;
  while (base < MROWS) {
    const int nAct = (MROWS - base < 64 * RPL) ? (MROWS - base) : 64 * RPL;

    if (base == prefBase) {
#pragma unroll
      for (int q = 0; q < RPL; ++q)
#pragma unroll
        for (int t = 0; t < KC; ++t) ci_[q][t] = ni_[q][t];
    } else {
#pragma unroll
      for (int q = 0; q < RPL; ++q) {
        int o = lane + 64 * q;
        int r = base + (o < nAct ? o : 0);
        const uint4* cr = (const uint4*)(cand + (size_t)r * KC);
        uint4 a = cr[0], b = cr[1];
        ci_[q][0] = a.x; ci_[q][1] = a.y; ci_[q][2] = a.z; ci_[q][3] = a.w;
        ci_[q][4] = b.x; ci_[q][5] = b.y; ci_[q][6] = b.z; ci_[q][7] = b.w;
      }
    }
    prefBase = base + nAct;  // predicted next base (full commit)
#pragma unroll
    for (int q = 0; q < RPL; ++q) {
      int pr = prefBase + lane + 64 * q;
      if (pr >= MROWS) pr = MROWS - 1;
      const uint4* cr = (const uint4*)(cand + (size_t)pr * KC);
      uint4 a = cr[0], b = cr[1];
      ni_[q][0] = a.x; ni_[q][1] = a.y; ni_[q][2] = a.z; ni_[q][3] = a.w;
      ni_[q][4] = b.x; ni_[q][5] = b.y; ni_[q][6] = b.z; ni_[q][7] = b.w;
    }

    // availability mask per row vs pass-start avail
    unsigned m[RPL];
#pragma unroll
    for (int q = 0; q < RPL; ++q) {
      int o = lane + 64 * q;
      unsigned mm = 0;
#pragma unroll
      for (int t = 0; t < KC; ++t) {
        unsigned g = ci_[q][t] >> 1;
        mm |= ((avail[g >> 5] >> (g & 31)) & 1u) << t;
      }
      m[q] = (o < nAct) ? mm : 0u;
    }

    // fixed-point conflict resolution (wave-lockstep; same-wave DS ops are ordered)
    unsigned pe[RPL];
    bool cl[RPL];
    bool forceSerial = false;
    int guard = 0;
    while (true) {
#pragma unroll
      for (int q = 0; q < RPL; ++q) {
        unsigned e = 0;
#pragma unroll
        for (int t = KC - 1; t >= 0; --t)
          if (m[q] & (1u << t)) e = ci_[q][t];
        pe[q] = e;
        cl[q] = (m[q] != 0u) && (e & 1u);   // sorted: first-available decides matched-ness
      }
#pragma unroll
      for (int q = 0; q < RPL; ++q)
        if (cl[q]) atomicMin(&claim[pe[q] >> 1], (unsigned)(lane + 64 * q));
      __builtin_amdgcn_wave_barrier();
      bool any = false;
      bool lost[RPL];
#pragma unroll
      for (int q = 0; q < RPL; ++q) {
        lost[q] = cl[q] && (claim[pe[q] >> 1] < (unsigned)(lane + 64 * q));
        any |= lost[q];
      }
      if (__ballot(any) == 0ull) break;
#pragma unroll
      for (int q = 0; q < RPL; ++q)
        if (lost[q]) m[q] &= (m[q] - 1u);  // drop stolen candidate, re-propose
      if (++guard > 2100) { forceSerial = true; break; }  // > max drops; exact safety
    }

    // first exhausted row offset (active row with no candidates left)
    unsigned fe = 1024u;
#pragma unroll
    for (int q = 0; q < RPL; ++q) {
      unsigned o = (unsigned)(lane + 64 * q);
      if (o < (unsigned)nAct && m[q] == 0u && o < fe) fe = o;
    }
#pragma unroll
    for (int off = 32; off >= 1; off >>= 1) {
      unsigned other = __shfl_xor(fe, off, 64);
      fe = other < fe ? other : fe;
    }
    int commitCount = forceSerial ? 0 : ((int)fe < nAct ? (int)fe : nAct);

#pragma unroll
    for (int q = 0; q < RPL; ++q) {
      int o = lane + 64 * q;
      if (o < commitCount) {
        unsigned g = pe[q] >> 1;
        match[base + o] = (cl[q] ? 0x80000000u : 0u) | g;
        if (cl[q]) atomicAnd(&avail[g >> 5], ~(1u << (g & 31)));
      }
    }
    // reset all claim slots we may have touched (idempotent; committed gts are
    // filtered by avail next pass)
#pragma unroll
    for (int q = 0; q < RPL; ++q)
#pragma unroll
      for (int t = 0; t < KC; ++t) claim[ci_[q][t] >> 1] = 0xFFFFFFFFu;
    __builtin_amdgcn_wave_barrier();

    base += commitCount;

    if (commitCount < nAct) {
      // row 'base': top-8 exhausted (or safety) -> exact full-scan argmin over avail,
      // in reference (d=sqrt(s), idx) space: bit-exact vs numpy.
      const int r = base;
      float fx = pred[(size_t)r * 7 + 0];
      float fy = pred[(size_t)r * 7 + 1];
      float fz = pred[(size_t)r * 7 + 2];
      unsigned long long best = ~0ull;
      for (int j0 = 0; j0 < NGT / 64; ++j0) {
        int j = j0 * 64 + lane;
        if ((avail[j >> 5] >> (j & 31)) & 1u) {
          unsigned db;
          {
#pragma clang fp contract(off)
            float dx = fx - sx[j];
            float dy = fy - sy[j];
            float dz = fz - sz[j];
            float s = (dx * dx + dy * dy) + dz * dz;
            db = __float_as_uint(sqrtf(s));
          }
          unsigned long long key = ((unsigned long long)db << 32) | (unsigned)j;
          if (key < best) best = key;
        }
      }
      unsigned long long mm2 = wave_min64(best);
      if (lane == 0) {
        if (mm2 == ~0ull) {
          match[r] = 0u;  // nothing available -> unmatched (masked; idx irrelevant)
        } else {
          unsigned db = (unsigned)(mm2 >> 32);
          unsigned j = (unsigned)mm2;
          bool ok = db < THRESH_BITS;
          if (ok) atomicAnd(&avail[j >> 5], ~(1u << (j & 31)));
          match[r] = (ok ? 0x80000000u : 0u) | j;
        }
      }
      __builtin_amdgcn_wave_barrier();
      base += 1;
    }
  }
}

// ---------------- Kernel C: loss terms + reduction ----------------
__device__ __forceinline__ float smooth_l1(float x) {
  float a = fabsf(x);
  return (a < 1.0f) ? (0.5f * a * a) : (a - 0.5f);
}

__global__ __launch_bounds__(256) void loss_kernel(const float* __restrict__ pred,
                                                   const float* __restrict__ gt,
                                                   const unsigned* __restrict__ match,
                                                   float* __restrict__ acc) {
  int i = blockIdx.x * 256 + threadIdx.x;
  float vc = 0.f, vs = 0.f, vo = 0.f, vi = 0.f, vk = 0.f;
  if (i < MROWS) {
    unsigned r = match[i];
    if (r & 0x80000000u) {
      unsigned j = r & 0x7FFFFFFFu;
      float p[7], g[7];
#pragma unroll
      for (int t = 0; t < 7; ++t) { p[t] = pred[i * 7 + t]; g[t] = gt[j * 7 + t]; }
      vc = smooth_l1(p[0] - g[0]) + smooth_l1(p[1] - g[1]) + smooth_l1(p[2] - g[2]);
      vs = smooth_l1(p[3] - g[3]) + smooth_l1(p[4] - g[4]) + smooth_l1(p[5] - g[5]);
      float d = p[6] - g[6];
      // atan2(sin d, cos d) == wrap to [-pi, pi]; smooth_l1 is even so boundary sign is moot
      float w = d - 6.283185307179586f * rintf(d * 0.15915494309189535f);
      vo = smooth_l1(w);
      float iw = fminf(p[0] + p[3] * 0.5f, g[0] + g[3] * 0.5f) -
                 fmaxf(p[0] - p[3] * 0.5f, g[0] - g[3] * 0.5f);
      iw = fmaxf(iw, 0.0f);
      float ih = fminf(p[1] + p[4] * 0.5f, g[1] + g[4] * 0.5f) -
                 fmaxf(p[1] - p[4] * 0.5f, g[1] - g[4] * 0.5f);
      ih = fmaxf(ih, 0.0f);
      float inter = iw * ih;
      float uni = p[3] * p[4] + g[3] * g[4] - inter;
      vi = 1.0f - inter / (uni + 1e-6f);
      vk = 1.0f;
    }
  }
#pragma unroll
  for (int off = 32; off >= 1; off >>= 1) {
    vc += __shfl_down(vc, off, 64);
    vs += __shfl_down(vs, off, 64);
    vo += __shfl_down(vo, off, 64);
    vi += __shfl_down(vi, off, 64);
    vk += __shfl_down(vk, off, 64);
  }
  if ((threadIdx.x & 63) == 0) {
    atomicAdd(&acc[0], vc);
    atomicAdd(&acc[1], vs);
    atomicAdd(&acc[2], vo);
    atomicAdd(&acc[3], vi);
    atomicAdd(&acc[4], vk);
  }
}

__global__ void finalize_kernel(const float* __restrict__ acc, float* __restrict__ out) {
  float k = fmaxf(acc[4], 1.0f);
  float loss = acc[0] / (3.0f * k)
             + 0.5f * (acc[1] / (3.0f * k) + acc[2] / k)
             + 2.0f * (acc[3] / k);
  out[0] = loss;
}

extern "C" void kernel_launch(void* const* d_in, const int* in_sizes, int n_in,
                              void* d_out, int out_size, void* d_ws, size_t ws_size,
                              hipStream_t stream) {
  const float* pred = (const float*)d_in[0];
  const float* gt   = (const float*)d_in[1];
  char* ws = (char*)d_ws;
  float* acc       = (float*)ws;                        // 32 B accumulators
  unsigned* match  = (unsigned*)(ws + 1024);            // 32 KB
  unsigned* cand   = (unsigned*)(ws + 33792);           // 256 KB packed candidates
  float4* cen      = (float4*)(ws + 295936);            // 128 KB packed centers

  hipMemsetAsync(acc, 0, 32, stream);
  pack_kernel<<<NGT / 256, 256, 0, stream>>>(gt, cen);
  topk_kernel<<<MROWS / (RPW * 4), 256, 0, stream>>>(pred, cen, cand);
  greedy_kernel<<<1, 64, 0, stream>>>(cand, pred, gt, match);
  loss_kernel<<<MROWS / 256, 256, 0, stream>>>(pred, gt, match, acc);
  finalize_kernel<<<1, 1, 0, stream>>>(acc, (float*)d_out);
}